// Round 12
// baseline (32.019 us; speedup 1.0000x reference)
//
#include <hip/hip_runtime.h>
#include <math.h>

// LightconvLayer: x (T,B,C) f32, weight (H,K) f32 -> out (T,B,C) f32
// out[t,b,c] = sum_k softmax(weight[c/64])[k] * x[t+k-30, b, c] (zero-pad left)
//
// R12 = R11 (wave-autonomous, float2 lanes, sliding reg window, no barriers)
// with prefetch depth 2 -> 3 (single-variable test of latency cover):
//  - wave owns (b, 128 ch = 2 heads, 64-row chunk); 8 tiles of TT=8
//  - ring[32][128] = 16 KB holds exactly L(j)..L(j+3) (32 slots)
//  - per tile: stage L(j+3) (4x width-16 gload_lds, 2 rows each), counted
//    own-vmcnt, 8x ds_read_b64, 496 FMA, 8x dwordx2 stores, slide window
//  - vmcnt ledger (in-order, L=4,S=8): j0=12,j1=20,j2=28,j3=36,j4=36,
//    j5=32,j6=28,j7=24
//  - alias note: stage(j+3) slots == window(j-1) slots; tile-top
//    sched_barrier(0) keeps its ISSUE after tile j-1's ds_reads, and the
//    LDS write lands >=900cy after issue -> no race.
#define T_LEN 2048
#define B_SZ  8
#define C_SZ  1024
#define NH    16
#define KW    31
#define HALO  (KW - 1)        // 30
#define TT    8
#define CHUNK 64              // rows per wave
#define NTILE (CHUNK / TT)    // 8
#define RING  32
#define WIN   (TT + HALO)     // 38
#define CGW   128             // channels per wave
#define ROWSTRIDE (B_SZ * C_SZ)  // 8192 floats between t rows

#define GLOBAL_AS(p) ((const __attribute__((address_space(1))) void*)(p))
#define LDS_AS(p)    ((__attribute__((address_space(3))) void*)(p))

__global__ __launch_bounds__(64, 3) void lightconv_kernel(
    const float* __restrict__ x, const float* __restrict__ weight,
    float* __restrict__ out) {
  __shared__ float ring[RING][CGW];  // 16 KB, wave-private (1 wave/block)
  const int lane = threadIdx.x;

  const int cgrp = blockIdx.x & 7;   // 128-ch group (C/128 = 8)
  const int tc   = blockIdx.x >> 3;  // t-chunk 0..31
  const int b    = blockIdx.y;
  const int c0   = cgrp * CGW;
  const int tb   = tc * CHUNK;       // tb % 32 == 0 -> compile-time slots

  // --- taps: per-lane (2 heads per wave). load + softmax in VGPRs ---
  const int head = cgrp * 2 + (lane >> 5);
  float wv[KW];
  float m = -1e30f;
#pragma unroll
  for (int k = 0; k < KW; ++k) {
    wv[k] = weight[head * KW + k];
    m = fmaxf(m, wv[k]);
  }
  float s = 0.f;
#pragma unroll
  for (int k = 0; k < KW; ++k) {
    wv[k] = expf(wv[k] - m);
    s += wv[k];
  }
  const float inv = 1.f / s;
  float wk[KW];
#pragma unroll
  for (int k = 0; k < KW; ++k) wk[k] = wv[k] * inv;

  const float* xbase = x + (size_t)b * C_SZ + c0;
  const float* xch   = xbase + 2 * lane;  // per-lane channel pair base
  // staging offset: lane l -> row (l>>5), ch (l&31)*4 floats (16 B)
  const int lane_off = (lane >> 5) * ROWSTRIDE + (lane & 31) * 4;

  // --- prologue ---
  // halo rows tb-30..tb-1 -> registers xv[0..29] (float2)
  float2 xv[WIN];
  if (tb == 0) {
#pragma unroll
    for (int i = 0; i < HALO; ++i) xv[i] = make_float2(0.f, 0.f);
  } else {
#pragma unroll
    for (int i = 0; i < HALO; ++i) {
      xv[i] = *(const float2*)&xch[(size_t)(tb - HALO + i) * ROWSTRIDE];
    }
  }
  // stage L(0),L(1),L(2): rows tb..tb+23 -> slots 0..23 (12 instrs)
#pragma unroll
  for (int r2 = 0; r2 < 12; ++r2) {
    const float* gp = xbase + (size_t)(tb + 2 * r2) * ROWSTRIDE + lane_off;
    __builtin_amdgcn_global_load_lds(GLOBAL_AS(gp), LDS_AS(&ring[2 * r2][0]),
                                     16, 0, 0);
  }

  // --- 8 tiles, fully unrolled, no barriers, counted own-vmcnt ---
#pragma unroll
  for (int j = 0; j < NTILE; ++j) {
    const int tstart = tb + j * TT;

    // tile-top fence: keep this tile's stage AFTER previous tile's ds_reads
    // (stage(j+3) slots alias window(j-1) slots)
    __builtin_amdgcn_sched_barrier(0);

    // stage L(j+3): rows tstart+24..31 -> slots (8j+24+2r2)&31 (compile-time)
    if (j <= NTILE - 4) {
#pragma unroll
      for (int r2 = 0; r2 < 4; ++r2) {
        const float* gp =
            xbase + (size_t)(tstart + 3 * TT + 2 * r2) * ROWSTRIDE + lane_off;
        __builtin_amdgcn_global_load_lds(
            GLOBAL_AS(gp), LDS_AS(&ring[(8 * j + 24 + 2 * r2) & (RING - 1)][0]),
            16, 0, 0);
      }
    }
    // counted wait: guarantee L(j) retired (in-order vmem retirement)
    if (j == 0)       asm volatile("s_waitcnt vmcnt(12)" ::: "memory");
    else if (j == 1)  asm volatile("s_waitcnt vmcnt(20)" ::: "memory");
    else if (j == 2)  asm volatile("s_waitcnt vmcnt(28)" ::: "memory");
    else if (j == 3)  asm volatile("s_waitcnt vmcnt(36)" ::: "memory");
    else if (j == 4)  asm volatile("s_waitcnt vmcnt(36)" ::: "memory");
    else if (j == 5)  asm volatile("s_waitcnt vmcnt(32)" ::: "memory");
    else if (j == 6)  asm volatile("s_waitcnt vmcnt(28)" ::: "memory");
    else              asm volatile("s_waitcnt vmcnt(24)" ::: "memory");
    __builtin_amdgcn_sched_barrier(0);  // rule #18: pin ds_reads below

    // read tile j's 8 new rows once (ds_read_b64, imm slot offsets)
#pragma unroll
    for (int i = 0; i < TT; ++i) {
      const float2* rp = (const float2*)&ring[(8 * j + i) & (RING - 1)][0];
      xv[HALO + i] = rp[lane];
    }
    // compute + store 8 outputs (dwordx2)
    float* opb = out + ((size_t)tstart * B_SZ + b) * C_SZ + c0 + 2 * lane;
#pragma unroll
    for (int o = 0; o < TT; ++o) {
      float ax = 0.f, ay = 0.f;
#pragma unroll
      for (int k = 0; k < KW; ++k) {
        ax = fmaf(wk[k], xv[o + k].x, ax);
        ay = fmaf(wk[k], xv[o + k].y, ay);
      }
      *(float2*)&opb[(size_t)o * ROWSTRIDE] = make_float2(ax, ay);
    }
    // slide window by TT (full unroll -> pure register renaming)
#pragma unroll
    for (int i = 0; i < HALO; ++i) xv[i] = xv[i + TT];
  }
}

extern "C" void kernel_launch(void* const* d_in, const int* in_sizes, int n_in,
                              void* d_out, int out_size, void* d_ws, size_t ws_size,
                              hipStream_t stream) {
  const float* x = (const float*)d_in[0];      // (T,B,C) f32
  const float* w = (const float*)d_in[1];      // (H,K) f32
  float* out = (float*)d_out;                  // (T,B,C) f32
  (void)in_sizes; (void)n_in; (void)out_size; (void)d_ws; (void)ws_size;

  dim3 grid((C_SZ / CGW) * (T_LEN / CHUNK), B_SZ);  // (256, 8) = 2048 waves
  dim3 block(64);
  lightconv_kernel<<<grid, block, 0, stream>>>(x, w, out);
}